// Round 4
// baseline (548.588 us; speedup 1.0000x reference)
//
#include <hip/hip_runtime.h>
#include <hip/hip_fp16.h>

// out[n,a,b] = sigmoid(w2 . leaky(w1 . leaky(u'[n,a,:] - v[n,b,:]) + b1) + b2)
// u' = za.w0^T + b0, v = zb.w0^T (precomputed f16).
// Main GEMM: A = w1 stationary in registers (rows = hidden1 g), B = hidden0
// fragments built on the fly in packed f16. No LDS in the GEMM.
// Block = 4 waves; wave ws owns g-slice [ws*64, ws*64+64) (2 MFMA row-tiles).
// Grid 512 = n(8) x bblk(8) x aoct(8); each block loops 32 a-values.

typedef float f32x16 __attribute__((ext_vector_type(16)));
typedef _Float16 f16x8 __attribute__((ext_vector_type(8)));

// ---------------------------------------------------------------------------
// Merged pack kernel.
// Blocks 0..2047: pack u' (f16 linear) + v (f16 B-frag-linear), nr = bid.
// Blocks 2048..2303: pack w1 into A-frag-linear f16.
// ---------------------------------------------------------------------------
__global__ __launch_bounds__(256) void pack_all(
    const float* __restrict__ za, const float* __restrict__ zb,
    const float* __restrict__ w0, const float* __restrict__ b0,
    const float* __restrict__ w1,
    _Float16* __restrict__ upack, _Float16* __restrict__ vpack,
    _Float16* __restrict__ w1pk) {
  int bid = blockIdx.x;
  int tid = threadIdx.x;
  if (bid < 2048) {
    int nr = bid;                   // n*256 + r
    int n = nr >> 8, r = nr & 255;
    __shared__ float arow[64], brow[64];
    if (tid < 64) arow[tid] = za[nr * 64 + tid];
    else if (tid < 128) brow[tid - 64] = zb[nr * 64 + (tid - 64)];
    __syncthreads();
    int h = tid;
    const float* w0r = w0 + h * 64;
    float ua = 0.f, vb = 0.f;
#pragma unroll
    for (int c = 0; c < 64; c += 4) {
      float4 w = *reinterpret_cast<const float4*>(w0r + c);
      ua += w.x * arow[c] + w.y * arow[c + 1] + w.z * arow[c + 2] + w.w * arow[c + 3];
      vb += w.x * brow[c] + w.y * brow[c + 1] + w.z * brow[c + 2] + w.w * brow[c + 3];
    }
    upack[nr * 256 + h] = (_Float16)(ua + b0[h]);
    // v B-frag-linear: frag (n, bblk=r>>5, kiter=h>>4); lane = (kh)*32 + (r&31)
    int bblk = r >> 5, lcol = r & 31;
    int kiter = h >> 4, rem = h & 15, lh = rem >> 3, j = rem & 7;
    int lane = lh * 32 + lcol;
    vpack[(((n * 8 + bblk) * 16 + kiter) * 64 + lane) * 8 + j] = (_Float16)vb;
  } else {
    int id = (bid - 2048) * 256 + tid;   // 0..65535
    int g = id >> 8, k = id & 255;
    int gt = g >> 5, lcol = g & 31;
    int kiter = k >> 4, rem = k & 15, lh = rem >> 3, j = rem & 7;
    int lane = lh * 32 + lcol;
    w1pk[((kiter * 8 + gt) * 64 + lane) * 8 + j] = (_Float16)w1[id];
  }
}

// ---------------------------------------------------------------------------
// Main fused kernel. 1KB ping-pong LDS for the cross-wave g-reduction only.
// ---------------------------------------------------------------------------
__global__ __launch_bounds__(256, 2) void fused_main(
    const _Float16* __restrict__ upack, const _Float16* __restrict__ vpack,
    const _Float16* __restrict__ w1pk,
    const float* __restrict__ b1, const float* __restrict__ w2,
    const float* __restrict__ b2, float* __restrict__ out) {
  __shared__ float lds_p[2][4][32];
  int bid = blockIdx.x;             // n(3b) | bblk(3b) | aoct(3b)
  int n = bid >> 6;
  int bblk = (bid >> 3) & 7;
  int aoct = bid & 7;
  int tid = threadIdx.x;
  int ws = tid >> 6;                // wave id: g-slice [ws*64, +64)
  int l = tid & 63;
  int l31 = l & 31, lh = l >> 5;

  // Stationary w1 A-fragments: 16 kiters x 2 g-tiles = 128 regs (AGPR-eligible).
  f16x8 w1f[16][2];
#pragma unroll
  for (int kt = 0; kt < 16; ++kt) {
#pragma unroll
    for (int t = 0; t < 2; ++t) {
      int gt = 2 * ws + t;
      w1f[kt][t] = *reinterpret_cast<const f16x8*>(w1pk + ((kt * 8 + gt) * 64 + l) * 8);
    }
  }
  float b2v = b2[0];

  const _Float16 c001 = (_Float16)0.01f;
  const f16x8 c001v = {c001, c001, c001, c001, c001, c001, c001, c001};

  const _Float16* vb = vpack + (size_t)((n * 8 + bblk) * 16) * 512 + l * 8;

  for (int it = 0; it < 32; ++it) {
    int a = aoct * 32 + it;
    const _Float16* ur = upack + (size_t)(n * 256 + a) * 256 + lh * 8;

    f32x16 acc0 = {0.f}, acc1 = {0.f};
#pragma unroll
    for (int r = 0; r < 16; ++r) { acc0[r] = 0.f; acc1[r] = 0.f; }

#pragma unroll 4
    for (int kt = 0; kt < 16; ++kt) {
      f16x8 uu = *reinterpret_cast<const f16x8*>(ur + kt * 16);
      f16x8 vv = *reinterpret_cast<const f16x8*>(vb + kt * 512);
      f16x8 d = uu - vv;                                   // v_pk_add_f16
      f16x8 r = __builtin_elementwise_max(d, d * c001v);   // leaky (pk mul+max)
      acc0 = __builtin_amdgcn_mfma_f32_32x32x16_f16(w1f[kt][0], r, acc0, 0, 0, 0);
      acc1 = __builtin_amdgcn_mfma_f32_32x32x16_f16(w1f[kt][1], r, acc1, 0, 0, 0);
    }

    // Epilogue: hidden1 = leaky(acc + b1); p = hidden1 . w2-slice (g in-lane)
    float p = 0.f;
#pragma unroll
    for (int rg = 0; rg < 4; ++rg) {
      int gbase0 = (2 * ws + 0) * 32 + 8 * rg + 4 * lh;
      int gbase1 = (2 * ws + 1) * 32 + 8 * rg + 4 * lh;
      float4 bb0 = *reinterpret_cast<const float4*>(b1 + gbase0);
      float4 ww0 = *reinterpret_cast<const float4*>(w2 + gbase0);
      float4 bb1 = *reinterpret_cast<const float4*>(b1 + gbase1);
      float4 ww1 = *reinterpret_cast<const float4*>(w2 + gbase1);
      float h;
      h = acc0[rg * 4 + 0] + bb0.x; h = fmaxf(h, 0.01f * h); p = fmaf(h, ww0.x, p);
      h = acc0[rg * 4 + 1] + bb0.y; h = fmaxf(h, 0.01f * h); p = fmaf(h, ww0.y, p);
      h = acc0[rg * 4 + 2] + bb0.z; h = fmaxf(h, 0.01f * h); p = fmaf(h, ww0.z, p);
      h = acc0[rg * 4 + 3] + bb0.w; h = fmaxf(h, 0.01f * h); p = fmaf(h, ww0.w, p);
      h = acc1[rg * 4 + 0] + bb1.x; h = fmaxf(h, 0.01f * h); p = fmaf(h, ww1.x, p);
      h = acc1[rg * 4 + 1] + bb1.y; h = fmaxf(h, 0.01f * h); p = fmaf(h, ww1.y, p);
      h = acc1[rg * 4 + 2] + bb1.z; h = fmaxf(h, 0.01f * h); p = fmaf(h, ww1.z, p);
      h = acc1[rg * 4 + 3] + bb1.w; h = fmaxf(h, 0.01f * h); p = fmaf(h, ww1.w, p);
    }
    p += __shfl_xor(p, 32, 64);     // fold the two lh halves (rows split by lh)

    int ph = it & 1;
    if (l < 32) lds_p[ph][ws][l] = p;
    __syncthreads();
    if (ws == 0 && l < 32) {
      float s = lds_p[ph][0][l] + lds_p[ph][1][l] + lds_p[ph][2][l] + lds_p[ph][3][l] + b2v;
      out[(size_t)(n * 256 + a) * 256 + bblk * 32 + l] = 1.f / (1.f + __expf(-s));
    }
    // ping-pong: next iter writes the other phase; reuse is two barriers away
  }
}

extern "C" void kernel_launch(void* const* d_in, const int* in_sizes, int n_in,
                              void* d_out, int out_size, void* d_ws, size_t ws_size,
                              hipStream_t stream) {
  const float* za = (const float*)d_in[0];
  const float* zb = (const float*)d_in[1];
  const float* w0 = (const float*)d_in[2];
  const float* b0 = (const float*)d_in[3];
  const float* w1 = (const float*)d_in[4];
  const float* b1 = (const float*)d_in[5];
  const float* w2 = (const float*)d_in[6];
  const float* b2 = (const float*)d_in[7];
  float* out = (float*)d_out;

  char* ws = (char*)d_ws;
  _Float16* upack = (_Float16*)ws;                    // 1 MB
  _Float16* vpack = (_Float16*)(ws + (1u << 20));     // 1 MB
  _Float16* w1pk  = (_Float16*)(ws + (2u << 20));     // 128 KB

  pack_all<<<2304, 256, 0, stream>>>(za, zb, w0, b0, w1, upack, vpack, w1pk);
  fused_main<<<512, 256, 0, stream>>>(upack, vpack, w1pk, b1, w2, b2, out);
}

// Round 5
// 158.291 us; speedup vs baseline: 3.4657x; 3.4657x over previous
//
#include <hip/hip_runtime.h>
#include <hip/hip_fp16.h>

// out[n,a,b] = sigmoid(w2 . leaky(w1 . leaky(u'[n,a,:] - v[n,b,:]) + b1) + b2)
// u' = za.w0^T + b0, v = zb.w0^T (precomputed f16).
// Main GEMM: A = w1 stationary in registers (rows = hidden1 g), B = hidden0
// built on the fly in packed f16. No LDS in the GEMM loop.
// Block = 8 waves (512 thr); wave ws owns g-tile gt=ws (32 g, w1f[16]=64 regs).
// Grid 256 = n(8) x bblk(8) x aq(4); each block loops 64 a-values.

typedef float f32x16 __attribute__((ext_vector_type(16)));
typedef _Float16 f16x8 __attribute__((ext_vector_type(8)));

// ---------------------------------------------------------------------------
// Merged pack kernel.
// Blocks 0..2047: pack u' (f16 linear) + v (f16 B-frag-linear), nr = bid.
// Blocks 2048..2303: pack w1 into A-frag-linear f16.
// ---------------------------------------------------------------------------
__global__ __launch_bounds__(256) void pack_all(
    const float* __restrict__ za, const float* __restrict__ zb,
    const float* __restrict__ w0, const float* __restrict__ b0,
    const float* __restrict__ w1,
    _Float16* __restrict__ upack, _Float16* __restrict__ vpack,
    _Float16* __restrict__ w1pk) {
  int bid = blockIdx.x;
  int tid = threadIdx.x;
  if (bid < 2048) {
    int nr = bid;                   // n*256 + r
    int n = nr >> 8, r = nr & 255;
    __shared__ float arow[64], brow[64];
    if (tid < 64) arow[tid] = za[nr * 64 + tid];
    else if (tid < 128) brow[tid - 64] = zb[nr * 64 + (tid - 64)];
    __syncthreads();
    int h = tid;
    const float* w0r = w0 + h * 64;
    float ua = 0.f, vb = 0.f;
#pragma unroll
    for (int c = 0; c < 64; c += 4) {
      float4 w = *reinterpret_cast<const float4*>(w0r + c);
      ua += w.x * arow[c] + w.y * arow[c + 1] + w.z * arow[c + 2] + w.w * arow[c + 3];
      vb += w.x * brow[c] + w.y * brow[c + 1] + w.z * brow[c + 2] + w.w * brow[c + 3];
    }
    upack[nr * 256 + h] = (_Float16)(ua + b0[h]);
    // v B-frag-linear: frag (n, bblk=r>>5, kiter=h>>4); lane = lh*32 + (r&31)
    int bblk = r >> 5, lcol = r & 31;
    int kiter = h >> 4, rem = h & 15, lh = rem >> 3, j = rem & 7;
    int lane = lh * 32 + lcol;
    vpack[(((n * 8 + bblk) * 16 + kiter) * 64 + lane) * 8 + j] = (_Float16)vb;
  } else {
    int id = (bid - 2048) * 256 + tid;   // 0..65535
    int g = id >> 8, k = id & 255;
    int gt = g >> 5, lcol = g & 31;
    int kiter = k >> 4, rem = k & 15, lh = rem >> 3, j = rem & 7;
    int lane = lh * 32 + lcol;
    w1pk[((kiter * 8 + gt) * 64 + lane) * 8 + j] = (_Float16)w1[id];
  }
}

// ---------------------------------------------------------------------------
// Main fused kernel. LDS only for the cross-wave g-reduction (2KB ping-pong).
// ---------------------------------------------------------------------------
__global__ __launch_bounds__(512, 2) void fused_main(
    const _Float16* __restrict__ upack, const _Float16* __restrict__ vpack,
    const _Float16* __restrict__ w1pk,
    const float* __restrict__ b1, const float* __restrict__ w2,
    const float* __restrict__ b2, float* __restrict__ out) {
  __shared__ float lds_p[2][8][32];
  int bid = blockIdx.x;             // n(3b) | bblk(3b) | aq(2b)
  int n = bid >> 5;
  int bblk = (bid >> 2) & 7;
  int aq = bid & 3;
  int tid = threadIdx.x;
  int ws = tid >> 6;                // wave id = g-tile (32 g each)
  int l = tid & 63;
  int l31 = l & 31, lh = l >> 5;

  // Stationary w1 A-fragments for gt=ws: 16 x f16x8 = 64 regs. Static indices.
  f16x8 w1f[16];
#pragma unroll
  for (int kt = 0; kt < 16; ++kt)
    w1f[kt] = *reinterpret_cast<const f16x8*>(w1pk + ((kt * 8 + ws) * 64 + l) * 8);

  // Per-lane g-constants: g = ws*32 + 8*rg + 4*lh + i
  float b1f[16], w2f[16];
#pragma unroll
  for (int rg = 0; rg < 4; ++rg) {
    int gbase = ws * 32 + 8 * rg + 4 * lh;
    float4 bb = *reinterpret_cast<const float4*>(b1 + gbase);
    float4 ww = *reinterpret_cast<const float4*>(w2 + gbase);
    b1f[4 * rg + 0] = bb.x; b1f[4 * rg + 1] = bb.y;
    b1f[4 * rg + 2] = bb.z; b1f[4 * rg + 3] = bb.w;
    w2f[4 * rg + 0] = ww.x; w2f[4 * rg + 1] = ww.y;
    w2f[4 * rg + 2] = ww.z; w2f[4 * rg + 3] = ww.w;
  }
  float b2v = b2[0];

  const _Float16 c001 = (_Float16)0.01f;
  const f16x8 c001v = {c001, c001, c001, c001, c001, c001, c001, c001};

  const _Float16* vb = vpack + (size_t)((n * 8 + bblk) * 16) * 512 + l * 8;
  const _Float16* ub = upack + (size_t)(n * 256 + aq * 64) * 256 + lh * 8;

  for (int it = 0; it < 64; ++it) {
    const _Float16* ur = ub + (size_t)it * 256;

    f32x16 accA, accB;
#pragma unroll
    for (int r = 0; r < 16; ++r) { accA[r] = 0.f; accB[r] = 0.f; }

#pragma unroll
    for (int kt = 0; kt < 16; ++kt) {
      f16x8 uu = *reinterpret_cast<const f16x8*>(ur + kt * 16);
      f16x8 vv = *reinterpret_cast<const f16x8*>(vb + kt * 512);
      f16x8 d = uu - vv;                                   // v_pk_add_f16
      f16x8 r = __builtin_elementwise_max(d, d * c001v);   // leaky (pk mul+max)
      if (kt & 1)
        accB = __builtin_amdgcn_mfma_f32_32x32x16_f16(w1f[kt], r, accB, 0, 0, 0);
      else
        accA = __builtin_amdgcn_mfma_f32_32x32x16_f16(w1f[kt], r, accA, 0, 0, 0);
    }

    // Epilogue: hidden1 = leaky(acc + b1); partial p = hidden1 . w2 (16 g in-lane)
    float p = 0.f;
#pragma unroll
    for (int r = 0; r < 16; ++r) {
      float h = accA[r] + accB[r] + b1f[r];
      h = fmaxf(h, 0.01f * h);
      p = fmaf(h, w2f[r], p);
    }
    p += __shfl_xor(p, 32, 64);     // fold the two lh halves (g split by lh)

    int ph = it & 1;
    if (l < 32) lds_p[ph][ws][l] = p;
    __syncthreads();
    if (ws == 0 && l < 32) {
      float s = b2v;
#pragma unroll
      for (int w = 0; w < 8; ++w) s += lds_p[ph][w][l];
      int a = aq * 64 + it;
      out[(size_t)(n * 256 + a) * 256 + bblk * 32 + l] = 1.f / (1.f + __expf(-s));
    }
    // ping-pong: next iter writes the other buffer; one barrier per iter
  }
}

extern "C" void kernel_launch(void* const* d_in, const int* in_sizes, int n_in,
                              void* d_out, int out_size, void* d_ws, size_t ws_size,
                              hipStream_t stream) {
  const float* za = (const float*)d_in[0];
  const float* zb = (const float*)d_in[1];
  const float* w0 = (const float*)d_in[2];
  const float* b0 = (const float*)d_in[3];
  const float* w1 = (const float*)d_in[4];
  const float* b1 = (const float*)d_in[5];
  const float* w2 = (const float*)d_in[6];
  const float* b2 = (const float*)d_in[7];
  float* out = (float*)d_out;

  char* ws = (char*)d_ws;
  _Float16* upack = (_Float16*)ws;                    // 1 MB
  _Float16* vpack = (_Float16*)(ws + (1u << 20));     // 1 MB
  _Float16* w1pk  = (_Float16*)(ws + (2u << 20));     // 128 KB

  pack_all<<<2304, 256, 0, stream>>>(za, zb, w0, b0, w1, upack, vpack, w1pk);
  fused_main<<<256, 512, 0, stream>>>(upack, vpack, w1pk, b1, w2, b2, out);
}